// Round 13
// baseline (1062.318 us; speedup 1.0000x reference)
//
#include <hip/hip_runtime.h>
#include <math.h>

typedef _Float16 h8 __attribute__((ext_vector_type(8)));
typedef _Float16 h2 __attribute__((ext_vector_type(2)));
typedef float f32x4 __attribute__((ext_vector_type(4)));
typedef unsigned u32x2 __attribute__((ext_vector_type(2)));
typedef unsigned u32x4 __attribute__((ext_vector_type(4)));

__device__ __forceinline__ float clampf(float x, float lo, float hi) {
    return fminf(fmaxf(x, lo), hi);
}

__global__ void zero_ints(int* __restrict__ p, int n) {
    int i = blockIdx.x * 256 + threadIdx.x;
    if (i < n) p[i] = 0;
}

// fp16 B repack for CIN=64 layers, frag-major physical k' (= p) layout:
// p < 4096:  tile = p>>8 (mt = tile>>2, ct = tile&3); g = (p>>6)&3;
//            m = (p>>2)&15; i = p&3; bin = mt*16+g*4+i; c = ct*16+m -> cw[bin][c]
// p >= 4096: fw row c = p-4096   (4096..4159; 130 K-steps * 32 = 4160 exactly)
__global__ void repack_wh(const float* __restrict__ cw, const float* __restrict__ fw,
                          _Float16* __restrict__ Wh) {
    int idx = blockIdx.x * 256 + threadIdx.x;
    int total = 4 * 130 * 512;
    if (idx >= total) return;
    int j8 = idx & 7;
    int l = (idx >> 3) & 63;
    int rest = idx >> 9;
    int s = rest % 130;
    int t = rest / 130;
    int p = s * 32 + ((l >> 4) * 8) + j8;
    int co = t * 16 + (l & 15);
    float v = 0.f;
    if (p < 4096) {
        int tile = p >> 8;
        int g = (p >> 6) & 3;
        int m = (p >> 2) & 15;
        int i = p & 3;
        int mt = tile >> 2;
        int ct = tile & 3;
        int bin = mt * 16 + g * 4 + i;
        int c = ct * 16 + m;
        v = cw[(bin * 64 + c) * 64 + co];
    } else if (p < 4160) {
        v = fw[(p - 4096) * 64 + co];
    }
    Wh[idx] = (_Float16)v;
}

// Same p-layout, COUT=2 (layer 3).
__global__ void repack_wh3(const float* __restrict__ cw, const float* __restrict__ fw,
                           _Float16* __restrict__ Wh) {
    int idx = blockIdx.x * 256 + threadIdx.x;
    int total = 130 * 512;
    if (idx >= total) return;
    int j8 = idx & 7;
    int l = (idx >> 3) & 63;
    int s = idx >> 9;
    int p = s * 32 + ((l >> 4) * 8) + j8;
    int co = l & 15;
    float v = 0.f;
    if (co < 2) {
        if (p < 4096) {
            int tile = p >> 8;
            int g = (p >> 6) & 3;
            int m = (p >> 2) & 15;
            int i = p & 3;
            int mt = tile >> 2;
            int ct = tile & 3;
            int bin = mt * 16 + g * 4 + i;
            int c = ct * 16 + m;
            v = cw[(bin * 64 + c) * 2 + co];
        } else if (p < 4160) {
            v = fw[(p - 4096) * 2 + co];
        }
    }
    Wh[idx] = (_Float16)v;
}

// Layer-0 combined weight repack. p<256: bin = p&63, c = p>>6 (Cin=4);
// p in [256,260): dense row c' = p-256; p>=260: pad 0.
// cols co<32 = lin (fw0), co>=32 = conv (cw0).
__global__ void repack_w0h(const float* __restrict__ cw0, const float* __restrict__ fw0,
                           _Float16* __restrict__ Wh) {
    int idx = blockIdx.x * 256 + threadIdx.x;
    int total = 4 * 9 * 512;
    if (idx >= total) return;
    int j8 = idx & 7;
    int l = (idx >> 3) & 63;
    int rest = idx >> 9;
    int s = rest % 9;
    int t = rest / 9;
    int p = s * 32 + ((l >> 4) * 8) + j8;
    int co = t * 16 + (l & 15);
    float v = 0.f;
    if (p < 256) {
        int bin = p & 63;
        int c = p >> 6;
        if (co >= 32) v = cw0[(bin * 4 + c) * 32 + (co - 32)];
    } else if (p < 260) {
        int c = p - 256;
        if (co < 32) v = fw0[c * 32 + co];
    }
    Wh[idx] = (_Float16)v;
}

__global__ void edge_hist(const int* __restrict__ ei, const int* __restrict__ ej,
                          int* __restrict__ counts, int E) {
    int e = blockIdx.x * 256 + threadIdx.x;
    if (e >= E) return;
    int i = ei[e], j = ej[e];
    if (i != j) atomicAdd(&counts[i], 1);
}

__global__ __launch_bounds__(1024) void scan_kernel(const int* __restrict__ counts,
                                                    int* __restrict__ offs,
                                                    int* __restrict__ cursor, int N) {
    __shared__ int sums[1024];
    const int t = threadIdx.x;
    const int per = (N + 1023) / 1024;
    const int lo = t * per;
    const int hi = min(lo + per, N);
    int s = 0;
    for (int i = lo; i < hi; ++i) s += counts[i];
    sums[t] = s;
    __syncthreads();
    for (int d = 1; d < 1024; d <<= 1) {
        int v = (t >= d) ? sums[t - d] : 0;
        __syncthreads();
        sums[t] += v;
        __syncthreads();
    }
    int run = (t > 0) ? sums[t - 1] : 0;
    for (int i = lo; i < hi; ++i) {
        offs[i] = run;
        cursor[i] = run;
        run += counts[i];
    }
    if (t == 1023) offs[N] = sums[1023];
}

// csr_all[e] = uint4:
//   .x = j[0:17) | r0>>1 [17:19) | r1>>1 [19:21) | iv [21:24)
//   .z = fp16x2 {wu0*gv, wu0*fv}   (even u-row r0 taps at iv, iv+1)
//   .w = fp16x2 {wu1*gv, wu1*fv}   (odd  u-row r1 taps at iv, iv+1)
__global__ void edge_scatter(const int* __restrict__ ei, const int* __restrict__ ej,
                             const float* __restrict__ pos, int* __restrict__ cursor,
                             uint4* __restrict__ csr_all, int E) {
    int e = blockIdx.x * 256 + threadIdx.x;
    if (e >= E) return;
    int i = ei[e], j = ej[e];
    if (i == j) return;
    float dx = clampf(pos[i * 2 + 0] - pos[j * 2 + 0], -1.f, 1.f);
    float dy = clampf(pos[i * 2 + 1] - pos[j * 2 + 1], -1.f, 1.f);
    float r = sqrtf(dx * dx + dy * dy + 1e-12f);
    float u = clampf(2.f * r - 1.f, -1.f, 1.f);
    float v = atan2f(dy, dx) * 0.3183098861837907f;  // / pi
    float tu = (u + 1.f) * 3.5f;
    float tv = (v + 1.f) * 3.5f;
    int iu = min(6, max(0, (int)floorf(tu)));
    int iv = min(6, max(0, (int)floorf(tv)));
    float fu = clampf(tu - (float)iu, 0.f, 1.f);
    float fv = clampf(tv - (float)iv, 0.f, 1.f);
    bool even = (iu & 1) == 0;
    int rowi0 = even ? iu : iu + 1;  // even u-row
    int rowi1 = even ? iu + 1 : iu;  // odd u-row
    float wu0 = even ? (1.f - fu) : fu;
    float wu1 = even ? fu : (1.f - fu);
    float gv = 1.f - fv;
    unsigned a0 = (unsigned)__builtin_bit_cast(unsigned short, (_Float16)(wu0 * gv)) |
                  ((unsigned)__builtin_bit_cast(unsigned short, (_Float16)(wu0 * fv)) << 16);
    unsigned a1 = (unsigned)__builtin_bit_cast(unsigned short, (_Float16)(wu1 * gv)) |
                  ((unsigned)__builtin_bit_cast(unsigned short, (_Float16)(wu1 * fv)) << 16);
    int p = atomicAdd(&cursor[i], 1);
    csr_all[p] = make_uint4(
        (unsigned)j | ((unsigned)(rowi0 >> 1) << 17) | ((unsigned)(rowi1 >> 1) << 19) |
            ((unsigned)iv << 21),
        0u, a0, a1);
}

// ---------------------------------------------------------------------------
// Shared phase 1 with 1-deep register input pipeline. r7-verified layouts:
//   A = basis [64 bins x 32 e] fp16, zeroed + 4-tap sparse scatter.
//   B = gathered xh rows, subtiled [sub=(e>>2)*4+(c>>4)][e&3][c&15].
//   B-frags via ds_read_b64_tr_b16 chunk-gather (addr = tile_base + m*8).
// Pipeline: csr runs 2 tiles ahead, x-gather 1 tile ahead, all in registers
// (+~40 VGPR — FREE: kernel is LDS-bound to 1 block/CU, HW grants 128/wave at
// 1024 thr and r12 used only 64). At tile t: issue gather(t+1) [csr(t+1)
// returned a full tile ago] + csr(t+2), then compute t — the 600-900-cyc
// csr->shfl->gather chain leaves the straggler wave's critical path.
// LDS stays single-buffered: in-order DS ops + the pre-MFMA lgkmcnt(0) make
// next-iteration staging safe. Guarded dead prefetches for 1-tile nodes.
// Rule #18: lgkmcnt(0) + sched_barrier(0) between tr reads and MFMAs.
__device__ __forceinline__ void mom_phase1_64(
    const _Float16* __restrict__ xh, const uint4* __restrict__ csr_all,
    _Float16* Ast, _Float16* Bst, unsigned bst_byte,
    int e0, int e1, int lane, f32x4* acc) {
    const int half = lane >> 5;
    const int el = lane & 31;
    const int q = lane >> 4;
    const int m = lane & 15;

    // ---- pipeline prologue: tile 0 csr+gather, tile 1 csr
    bool ok = (e0 + el) < e1;
    uint4 ca = csr_all[ok ? e0 + el : e0];
    uint4 bv[4];
    {
        int jme = ok ? (int)(ca.x & 0x1FFFF) : -1;
#pragma unroll
        for (int it = 0; it < 4; ++it) {
            int ee = it * 8 + (lane >> 3);
            int jj = __shfl(jme, ee);
            int c0 = (lane & 7) * 8;
            uint4 t = make_uint4(0, 0, 0, 0);
            if (jj >= 0) t = *(const uint4*)(xh + (size_t)jj * 64 + c0);
            bv[it] = t;
        }
    }
    bool okn = (e0 + 32 + el) < e1;
    uint4 ca_n = csr_all[okn ? e0 + 32 + el : e0];

    for (int bs = e0; bs < e1; bs += 32) {
        // ---- issue tile t+1 gather + tile t+2 csr (fly under tile t work)
        uint4 bv_n[4];
        {
            int jme_n = okn ? (int)(ca_n.x & 0x1FFFF) : -1;
#pragma unroll
            for (int it = 0; it < 4; ++it) {
                int ee = it * 8 + (lane >> 3);
                int jj = __shfl(jme_n, ee);
                int c0 = (lane & 7) * 8;
                uint4 t = make_uint4(0, 0, 0, 0);
                if (jj >= 0) t = *(const uint4*)(xh + (size_t)jj * 64 + c0);
                bv_n[it] = t;
            }
        }
        bool oknn = (bs + 64 + el) < e1;
        uint4 ca_nn = csr_all[oknn ? bs + 64 + el : e0];

        // ---- tile t compute (uses ca, bv — both resident)
        {  // zero A (4 KB)
            uint4 z4 = make_uint4(0, 0, 0, 0);
#pragma unroll
            for (int zz = 0; zz < 4; ++zz) ((uint4*)Ast)[zz * 64 + lane] = z4;
        }
        {  // A scatter: lanes 0..31 even-row taps, 32..63 odd-row taps
            int iv = (ca.x >> 21) & 7;
            int rowi = half ? (int)((((ca.x >> 19) & 3) << 1) + 1)
                            : (int)(((ca.x >> 17) & 3) << 1);
            h2 wts = __builtin_bit_cast(h2, half ? ca.w : ca.z);
            if (ok) {
                int bin0 = rowi * 8 + iv;
                int bin1 = bin0 + 1;
                int a0 = bin0 * 32 + (((el >> 3) + (bin0 >> 1)) & 3) * 8 + (el & 7);
                int a1 = bin1 * 32 + (((el >> 3) + (bin1 >> 1)) & 3) * 8 + (el & 7);
                Ast[a0] = wts[0];
                Ast[a1] = wts[1];
            }
        }
        // B stage (b128 writes)
#pragma unroll
        for (int it = 0; it < 4; ++it) {
            int ee = it * 8 + (lane >> 3);
            int c0 = (lane & 7) * 8;
            int sub = (ee >> 2) * 4 + (c0 >> 4);
            ((uint4*)Bst)[sub * 8 + (ee & 3) * 2 + ((c0 >> 3) & 1)] = bv[it];
        }
        // A-frags (b128, compiler-scheduled; stores above alias -> ordered)
        h8 af[4];
#pragma unroll
        for (int mt = 0; mt < 4; ++mt) {
            int binr = mt * 16 + m;
            int aoff = binr * 32 + ((q + (binr >> 1)) & 3) * 8;
            af[mt] = *(const h8*)(Ast + aoff);
        }
        // B-frags via HW transpose read (chunk addr = tile_base + m*8)
        unsigned bb = bst_byte + (unsigned)(q * 1024 + m * 8);
        h8 bf[4];
#pragma unroll
        for (int ct = 0; ct < 4; ++ct) {
            u32x2 lo, hi;
            asm volatile("ds_read_b64_tr_b16 %0, %2 offset:%3\n\t"
                         "ds_read_b64_tr_b16 %1, %2 offset:%4"
                         : "=&v"(lo), "=&v"(hi)
                         : "v"(bb), "i"(ct * 128), "i"(ct * 128 + 512)
                         : "memory");
            u32x4 t;
            t[0] = lo[0]; t[1] = lo[1]; t[2] = hi[0]; t[3] = hi[1];
            bf[ct] = __builtin_bit_cast(h8, t);
        }
        asm volatile("s_waitcnt lgkmcnt(0)" ::: "memory");
        __builtin_amdgcn_sched_barrier(0);
        __builtin_amdgcn_s_setprio(1);
#pragma unroll
        for (int mt = 0; mt < 4; ++mt)
#pragma unroll
            for (int ct = 0; ct < 4; ++ct)
                acc[mt * 4 + ct] = __builtin_amdgcn_mfma_f32_16x16x32_f16(
                    af[mt], bf[ct], acc[mt * 4 + ct], 0, 0, 0);
        __builtin_amdgcn_s_setprio(0);

        // ---- rotate pipeline state
        ok = okn;
        ca = ca_n;
        okn = oknn;
        ca_n = ca_nn;
#pragma unroll
        for (int it = 0; it < 4; ++it) bv[it] = bv_n[it];
    }
}

// Writeback acc[16] -> frag-major p-layout (p = t*256 + g*64 + m*4 + i), fp16.
__device__ __forceinline__ void mom_writeback_64(const f32x4* acc, _Float16* momrow,
                                                 int lane) {
#pragma unroll
    for (int t = 0; t < 16; ++t) {
        h2 lo = {(_Float16)acc[t][0], (_Float16)acc[t][1]};
        h2 hi = {(_Float16)acc[t][2], (_Float16)acc[t][3]};
        h2* dst = (h2*)(momrow + t * 256 + (lane >> 4) * 64 + (lane & 15) * 4);
        dst[0] = lo;
        dst[1] = hi;
    }
}

// ---------------------------------------------------------------------------
// Layers 1..2 (CIN=64, COUT=64). r7 structure: TM=16, 1024 thr, 133.9 KB LDS,
// 1 block/CU — proven best vs r9 (TM=8: confounded, doubled per-block Wh L2
// traffic = +48 us, matching the +45 us regression), r10 (ILP via block
// reshape: lost TLP), r11 (split stream + perm: more FETCH + scattered
// writes). This round: register input pipeline INSIDE the r7 shape (VGPRs
// 64->128 are free at 1 block/CU).
// MODE 1: out32 = gemm+cb+fb (residual src), xh_out = fp16(relu(out32))
// MODE 2: res += x32 (residual); only xh_out written.
template <int MODE>
__global__ __launch_bounds__(1024, 4) void conv64_mfma(
    const _Float16* __restrict__ xh, const float* __restrict__ x32,
    const _Float16* __restrict__ Wh,
    const float* __restrict__ cb, const float* __restrict__ fb,
    const int* __restrict__ offs, const uint4* __restrict__ csr_all,
    float* __restrict__ out32, _Float16* __restrict__ xh_out, int nNodes) {
    constexpr int TM = 16;
    constexpr int KSTEPS = 130;
    constexpr int RSH = 4184;            // halfs per node row (8368 B)
    extern __shared__ _Float16 smem[];   // 16 * 4184 * 2 = 133888 B
    const int tid = threadIdx.x;
    const int w = tid >> 6;
    const int lane = tid & 63;
    const int base = blockIdx.x * TM;
    const int n = base + w;

    _Float16* Ast = smem + w * RSH;      // 2048 halfs staging (overlays mom row)
    _Float16* Bst = Ast + 2048;          // 2048 halfs
    const unsigned bst_byte = (unsigned)((w * RSH + 2048) * 2);

    f32x4 acc[16] = {{0, 0, 0, 0}, {0, 0, 0, 0}, {0, 0, 0, 0}, {0, 0, 0, 0},
                     {0, 0, 0, 0}, {0, 0, 0, 0}, {0, 0, 0, 0}, {0, 0, 0, 0},
                     {0, 0, 0, 0}, {0, 0, 0, 0}, {0, 0, 0, 0}, {0, 0, 0, 0},
                     {0, 0, 0, 0}, {0, 0, 0, 0}, {0, 0, 0, 0}, {0, 0, 0, 0}};

    if (n < nNodes) {
        mom_phase1_64(xh, csr_all, Ast, Bst, bst_byte, offs[n], offs[n + 1], lane, acc);
        mom_writeback_64(acc, smem + w * RSH, lane);
        smem[w * RSH + 4096 + lane] = xh[(size_t)n * 64 + lane];  // dense row
    }

    // ---- phase 2: K-chunk for this wave (130 = 2*9 + 14*8)
    const int s0 = w * 8 + min(w, 2);
    const int s_end = s0 + 8 + (w < 2 ? 1 : 0);
    const int quad = lane >> 4;
    const _Float16* arow = smem + (lane & 15) * RSH;

    const uint4* Bp = (const uint4*)Wh;
    uint4 b0[4], b1[4];
#pragma unroll
    for (int t = 0; t < 4; ++t) {  // global prefetch (no LDS dep) before barrier
        b0[t] = Bp[((size_t)t * KSTEPS + s0) * 64 + lane];
        b1[t] = Bp[((size_t)t * KSTEPS + s0 + 1) * 64 + lane];
    }
    __syncthreads();
    f32x4 acc2[4] = {{0, 0, 0, 0}, {0, 0, 0, 0}, {0, 0, 0, 0}, {0, 0, 0, 0}};
    for (int s = s0; s < s_end; ++s) {
        uint4 bq[4];
#pragma unroll
        for (int t = 0; t < 4; ++t) {
            bq[t] = b0[t];
            b0[t] = b1[t];
            if (s + 2 < s_end) b1[t] = Bp[((size_t)t * KSTEPS + s + 2) * 64 + lane];
        }
        h8 a = *(const h8*)(arow + s * 32 + quad * 8);
#pragma unroll
        for (int t = 0; t < 4; ++t)
            acc2[t] = __builtin_amdgcn_mfma_f32_16x16x32_f16(a, __builtin_bit_cast(h8, bq[t]),
                                                             acc2[t], 0, 0, 0);
    }
    __syncthreads();  // moments dead -> reuse as reduce scratch (64 KB)
    f32x4* red = (f32x4*)smem;
#pragma unroll
    for (int t = 0; t < 4; ++t) red[(w * 4 + t) * 64 + lane] = acc2[t];
    __syncthreads();
    if (w < 4) {
        f32x4 s = {0, 0, 0, 0};
#pragma unroll
        for (int g = 0; g < 16; ++g) s += red[(g * 4 + w) * 64 + lane];
        const int co = w * 16 + (lane & 15);
#pragma unroll
        for (int i = 0; i < 4; ++i) {
            int nn = base + quad * 4 + i;
            if (nn < nNodes) {
                float res = s[i] + cb[co] + fb[co];
                if (MODE == 2) res += x32[(size_t)nn * 64 + co];
                if (MODE == 1) out32[(size_t)nn * 64 + co] = res;
                xh_out[(size_t)nn * 64 + co] = (_Float16)fmaxf(res, 0.f);
            }
        }
    }
}

// ---------------------------------------------------------------------------
// Layer 3 (CIN=64, COUT=2): same phase 1 as conv64; phase 2 = 1 MFMA t-tile
// (cols 0..1 real). out = (gemm + cb3 + fb3) / 128.
__global__ __launch_bounds__(1024, 4) void conv_last_mfma(
    const _Float16* __restrict__ xh, const _Float16* __restrict__ Wh3,
    const float* __restrict__ cb3, const float* __restrict__ fb3,
    const int* __restrict__ offs, const uint4* __restrict__ csr_all,
    float* __restrict__ out, int nNodes) {
    constexpr int TM = 16;
    constexpr int RSH = 4184;
    extern __shared__ _Float16 smem[];   // 133888 B
    const int tid = threadIdx.x;
    const int w = tid >> 6;
    const int lane = tid & 63;
    const int base = blockIdx.x * TM;
    const int n = base + w;

    _Float16* Ast = smem + w * RSH;
    _Float16* Bst = Ast + 2048;
    const unsigned bst_byte = (unsigned)((w * RSH + 2048) * 2);

    f32x4 acc[16] = {{0, 0, 0, 0}, {0, 0, 0, 0}, {0, 0, 0, 0}, {0, 0, 0, 0},
                     {0, 0, 0, 0}, {0, 0, 0, 0}, {0, 0, 0, 0}, {0, 0, 0, 0},
                     {0, 0, 0, 0}, {0, 0, 0, 0}, {0, 0, 0, 0}, {0, 0, 0, 0},
                     {0, 0, 0, 0}, {0, 0, 0, 0}, {0, 0, 0, 0}, {0, 0, 0, 0}};

    if (n < nNodes) {
        mom_phase1_64(xh, csr_all, Ast, Bst, bst_byte, offs[n], offs[n + 1], lane, acc);
        mom_writeback_64(acc, smem + w * RSH, lane);
        smem[w * RSH + 4096 + lane] = xh[(size_t)n * 64 + lane];  // dense (relu'd)
    }

    const int s0 = w * 8 + min(w, 2);
    const int s_end = s0 + 8 + (w < 2 ? 1 : 0);
    const int quad = lane >> 4;
    const _Float16* arow = smem + (lane & 15) * RSH;
    const uint4* Bp = (const uint4*)Wh3;

    __syncthreads();
    f32x4 acc2 = {0, 0, 0, 0};
    for (int s = s0; s < s_end; ++s) {
        uint4 bq = Bp[(size_t)s * 64 + lane];
        h8 a = *(const h8*)(arow + s * 32 + quad * 8);
        acc2 = __builtin_amdgcn_mfma_f32_16x16x32_f16(a, __builtin_bit_cast(h8, bq),
                                                      acc2, 0, 0, 0);
    }
    __syncthreads();
    f32x4* red = (f32x4*)smem;
    red[w * 64 + lane] = acc2;
    __syncthreads();
    if (w == 0) {
        f32x4 s = {0, 0, 0, 0};
#pragma unroll
        for (int g = 0; g < 16; ++g) s += red[g * 64 + lane];
        const int co = lane & 15;
        if (co < 2) {
#pragma unroll
            for (int i = 0; i < 4; ++i) {
                int nn = base + quad * 4 + i;
                if (nn < nNodes)
                    out[nn * 2 + co] = (s[i] + cb3[co] + fb3[co]) * (1.f / 128.f);
            }
        }
    }
}

// ---------------------------------------------------------------------------
// Layer 0 (CIN=4, raw f32 x, no relu): shrunk moment-GEMM (r12 version,
// unchanged — risk containment).
__global__ __launch_bounds__(1024, 4) void conv0_mfma(
    const float* __restrict__ xf, const _Float16* __restrict__ W0h,
    const float* __restrict__ cb0, const float* __restrict__ fb0,
    const int* __restrict__ offs, const uint4* __restrict__ csr_all,
    _Float16* __restrict__ xh_out, int nNodes) {
    constexpr int TM = 16;
    constexpr int RSH0 = 296;
    constexpr int MOMSZ = 16 * RSH0;     // 4736 halfs
    extern __shared__ _Float16 smem[];   // (4736 + 16*2560)*2 = 91392 B
    const int tid = threadIdx.x;
    const int w = tid >> 6;
    const int lane = tid & 63;
    const int base = blockIdx.x * TM;
    const int n = base + w;

    _Float16* Ast = smem + MOMSZ + w * 2560;
    _Float16* Bst = Ast + 2048;
    _Float16* momrow = smem + w * RSH0;
    const unsigned bst_byte = (unsigned)((MOMSZ + w * 2560 + 2048) * 2);

    f32x4 acc[4] = {{0, 0, 0, 0}, {0, 0, 0, 0}, {0, 0, 0, 0}, {0, 0, 0, 0}};

    if (n < nNodes) {
        const int e0 = offs[n], e1 = offs[n + 1];
        const int half = lane >> 5;
        const int el = lane & 31;
        const int q = lane >> 4;
        const int m = lane & 15;
        for (int bs = e0; bs < e1; bs += 32) {
            {  // zero A
                uint4 z4 = make_uint4(0, 0, 0, 0);
#pragma unroll
                for (int zz = 0; zz < 4; ++zz) ((uint4*)Ast)[zz * 64 + lane] = z4;
            }
            int e = bs + el;
            bool ok = e < e1;
            uint4 ca = csr_all[ok ? e : e0];
            int jme = ok ? (int)(ca.x & 0x1FFFF) : -1;
            {
                int iv = (ca.x >> 21) & 7;
                int rowi = half ? (int)((((ca.x >> 19) & 3) << 1) + 1)
                                : (int)(((ca.x >> 17) & 3) << 1);
                h2 wts = __builtin_bit_cast(h2, half ? ca.w : ca.z);
                if (ok) {
                    int bin0 = rowi * 8 + iv;
                    int bin1 = bin0 + 1;
                    int a0 = bin0 * 32 + (((el >> 3) + (bin0 >> 1)) & 3) * 8 + (el & 7);
                    int a1 = bin1 * 32 + (((el >> 3) + (bin1 >> 1)) & 3) * 8 + (el & 7);
                    Ast[a0] = wts[0];
                    Ast[a1] = wts[1];
                }
            }
            // B: one edge per half-0 lane; 4 real cols + 12 zeros.
            if (half == 0) {
                float4 xj = make_float4(0.f, 0.f, 0.f, 0.f);
                if (jme >= 0) xj = *(const float4*)(xf + (size_t)jme * 4);
                h2 d0 = {(_Float16)xj.x, (_Float16)xj.y};
                h2 d1 = {(_Float16)xj.z, (_Float16)xj.w};
                uint4 bv = make_uint4(__builtin_bit_cast(unsigned, d0),
                                      __builtin_bit_cast(unsigned, d1), 0u, 0u);
                uint4* dst = (uint4*)Bst + (el >> 2) * 8 + (el & 3) * 2;
                dst[0] = bv;
                dst[1] = make_uint4(0, 0, 0, 0);
            }
            // A-frags
            h8 af[4];
#pragma unroll
            for (int mt = 0; mt < 4; ++mt) {
                int binr = mt * 16 + m;
                int aoff = binr * 32 + ((q + (binr >> 1)) & 3) * 8;
                af[mt] = *(const h8*)(Ast + aoff);
            }
            // B-frag via tr-read: chunk addr q*256 + m*8; subs 2q / 2q+1
            unsigned bb = bst_byte + (unsigned)(q * 256 + m * 8);
            u32x2 lo, hi;
            asm volatile("ds_read_b64_tr_b16 %0, %2 offset:0\n\t"
                         "ds_read_b64_tr_b16 %1, %2 offset:128"
                         : "=&v"(lo), "=&v"(hi)
                         : "v"(bb)
                         : "memory");
            u32x4 tt;
            tt[0] = lo[0]; tt[1] = lo[1]; tt[2] = hi[0]; tt[3] = hi[1];
            h8 b = __builtin_bit_cast(h8, tt);
            asm volatile("s_waitcnt lgkmcnt(0)" ::: "memory");
            __builtin_amdgcn_sched_barrier(0);
            __builtin_amdgcn_s_setprio(1);
#pragma unroll
            for (int mt = 0; mt < 4; ++mt)
                acc[mt] = __builtin_amdgcn_mfma_f32_16x16x32_f16(af[mt], b, acc[mt], 0, 0, 0);
            __builtin_amdgcn_s_setprio(0);
        }
        // writeback: p = bin + 64*c, only c = lane&15 < 4 valid
        if ((lane & 15) < 4) {
#pragma unroll
            for (int mt = 0; mt < 4; ++mt) {
                _Float16* dst = momrow + mt * 16 + (lane >> 4) * 4 + 64 * (lane & 15);
                ((h2*)dst)[0] = h2{(_Float16)acc[mt][0], (_Float16)acc[mt][1]};
                ((h2*)dst)[1] = h2{(_Float16)acc[mt][2], (_Float16)acc[mt][3]};
            }
        }
        if (lane < 7) {  // zero pad p in [260, 288)
            h2 z = {(_Float16)0.f, (_Float16)0.f};
            h2* zp = (h2*)(momrow + 260 + lane * 4);
            zp[0] = z;
            zp[1] = z;
        }
        if (lane < 4) momrow[256 + lane] = (_Float16)xf[(size_t)n * 4 + lane];  // dense raw
    }

    // phase 2: 9 K-steps over 16 waves (waves 9..15 idle)
    const int quad = lane >> 4;
    const _Float16* arow = smem + (lane & 15) * RSH0;
    const uint4* Bp = (const uint4*)W0h;
    __syncthreads();
    f32x4 acc2[4] = {{0, 0, 0, 0}, {0, 0, 0, 0}, {0, 0, 0, 0}, {0, 0, 0, 0}};
    const int s0 = min(w, 9), s_end = min(w + 1, 9);
    for (int s = s0; s < s_end; ++s) {
        uint4 bq[4];
#pragma unroll
        for (int t = 0; t < 4; ++t) bq[t] = Bp[((size_t)t * 9 + s) * 64 + lane];
        h8 a = *(const h8*)(arow + s * 32 + quad * 8);
#pragma unroll
        for (int t = 0; t < 4; ++t)
            acc2[t] = __builtin_amdgcn_mfma_f32_16x16x32_f16(a, __builtin_bit_cast(h8, bq[t]),
                                                             acc2[t], 0, 0, 0);
    }
    __syncthreads();
    f32x4* red = (f32x4*)(smem + MOMSZ);  // overlays dead staging
#pragma unroll
    for (int t = 0; t < 4; ++t) red[(w * 4 + t) * 64 + lane] = acc2[t];
    __syncthreads();
    if (w < 4) {
        f32x4 s = {0, 0, 0, 0};
#pragma unroll
        for (int g = 0; g < 16; ++g) s += red[(g * 4 + w) * 64 + lane];
        const int co = w * 16 + (lane & 15);
        const float bias = (co < 32) ? fb0[co] : cb0[co - 32];
#pragma unroll
        for (int i = 0; i < 4; ++i) {
            int nn = base + quad * 4 + i;
            if (nn < nNodes)
                xh_out[(size_t)nn * 64 + co] = (_Float16)fmaxf(s[i] + bias, 0.f);
        }
    }
}

extern "C" void kernel_launch(void* const* d_in, const int* in_sizes, int n_in,
                              void* d_out, int out_size, void* d_ws, size_t ws_size,
                              hipStream_t stream) {
    const float* pos = (const float*)d_in[0];
    const float* feat = (const float*)d_in[1];
    const int* ei = (const int*)d_in[2];
    const int* ej = (const int*)d_in[3];
    const float* cw0 = (const float*)d_in[4];
    const float* cb0 = (const float*)d_in[5];
    const float* fw0 = (const float*)d_in[6];
    const float* fb0 = (const float*)d_in[7];
    const float* cw1 = (const float*)d_in[8];
    const float* cb1 = (const float*)d_in[9];
    const float* fw1 = (const float*)d_in[10];
    const float* fb1 = (const float*)d_in[11];
    const float* cw2 = (const float*)d_in[12];
    const float* cb2 = (const float*)d_in[13];
    const float* fw2 = (const float*)d_in[14];
    const float* fb2 = (const float*)d_in[15];
    const float* cw3 = (const float*)d_in[16];
    const float* cb3 = (const float*)d_in[17];
    const float* fw3 = (const float*)d_in[18];
    const float* fb3 = (const float*)d_in[19];
    float* outp = (float*)d_out;

    const int N = in_sizes[0] / 2;
    const int E = in_sizes[2];

    char* wsp = (char*)d_ws;
    size_t off = 0;
    auto alloc = [&](size_t bytes) -> void* {
        void* p = wsp + off;
        off = (off + bytes + 255) & ~(size_t)255;
        return p;
    };
    int* counts = (int*)alloc((size_t)N * 4);
    int* offs = (int*)alloc((size_t)(N + 1) * 4);
    int* cursor = (int*)alloc((size_t)N * 4);
    uint4* csr_all = (uint4*)alloc((size_t)E * 16);
    float* ansB = (float*)alloc((size_t)N * 64 * 4);       // layer-1 f32 (residual)
    _Float16* xh0 = (_Float16*)alloc((size_t)N * 64 * 2);  // conv0 out (relu fp16)
    _Float16* xhB = (_Float16*)alloc((size_t)N * 64 * 2);  // layer-1 relu fp16
    _Float16* xhC = (_Float16*)alloc((size_t)N * 64 * 2);  // layer-2 relu fp16
    _Float16* Wh1 = (_Float16*)alloc((size_t)4 * 130 * 512 * 2);
    _Float16* Wh2 = (_Float16*)alloc((size_t)4 * 130 * 512 * 2);
    _Float16* Wh3 = (_Float16*)alloc((size_t)130 * 512 * 2);
    _Float16* W0h = (_Float16*)alloc((size_t)4 * 9 * 512 * 2);
    (void)ws_size;
    (void)n_in;
    (void)out_size;

    const int BIG_LDS = 16 * 4184 * 2;             // 133888 B, 1 block/CU
    const int LDS0 = (16 * 296 + 16 * 2560) * 2;   // 91392 B
    hipFuncSetAttribute((const void*)&conv64_mfma<1>,
                        hipFuncAttributeMaxDynamicSharedMemorySize, BIG_LDS);
    hipFuncSetAttribute((const void*)&conv64_mfma<2>,
                        hipFuncAttributeMaxDynamicSharedMemorySize, BIG_LDS);
    hipFuncSetAttribute((const void*)&conv_last_mfma,
                        hipFuncAttributeMaxDynamicSharedMemorySize, BIG_LDS);
    hipFuncSetAttribute((const void*)&conv0_mfma,
                        hipFuncAttributeMaxDynamicSharedMemorySize, LDS0);

    zero_ints<<<dim3((N + 255) / 256), dim3(256), 0, stream>>>(counts, N);
    const int RT = 4 * 130 * 512;
    repack_wh<<<dim3((RT + 255) / 256), dim3(256), 0, stream>>>(cw1, fw1, Wh1);
    repack_wh<<<dim3((RT + 255) / 256), dim3(256), 0, stream>>>(cw2, fw2, Wh2);
    repack_wh3<<<dim3((130 * 512 + 255) / 256), dim3(256), 0, stream>>>(cw3, fw3, Wh3);
    repack_w0h<<<dim3((4 * 9 * 512 + 255) / 256), dim3(256), 0, stream>>>(cw0, fw0, W0h);
    edge_hist<<<dim3((E + 255) / 256), dim3(256), 0, stream>>>(ei, ej, counts, E);
    scan_kernel<<<dim3(1), dim3(1024), 0, stream>>>(counts, offs, cursor, N);
    edge_scatter<<<dim3((E + 255) / 256), dim3(256), 0, stream>>>(ei, ej, pos, cursor, csr_all, E);

    const int nb = (N + 15) / 16;
    conv0_mfma<<<dim3(nb), dim3(1024), LDS0, stream>>>(
        feat, W0h, cb0, fb0, offs, csr_all, xh0, N);
    conv64_mfma<1><<<dim3(nb), dim3(1024), BIG_LDS, stream>>>(
        xh0, (const float*)nullptr, Wh1, cb1, fb1, offs, csr_all, ansB, xhB, N);
    conv64_mfma<2><<<dim3(nb), dim3(1024), BIG_LDS, stream>>>(
        xhB, ansB, Wh2, cb2, fb2, offs, csr_all, (float*)nullptr, xhC, N);
    conv_last_mfma<<<dim3(nb), dim3(1024), BIG_LDS, stream>>>(
        xhC, Wh3, cb3, fb3, offs, csr_all, outp, N);
}

// Round 14
// 821.628 us; speedup vs baseline: 1.2929x; 1.2929x over previous
//
#include <hip/hip_runtime.h>
#include <math.h>

typedef _Float16 h8 __attribute__((ext_vector_type(8)));
typedef _Float16 h2 __attribute__((ext_vector_type(2)));
typedef float f32x4 __attribute__((ext_vector_type(4)));
typedef unsigned u32x2 __attribute__((ext_vector_type(2)));
typedef unsigned u32x4 __attribute__((ext_vector_type(4)));

__device__ __forceinline__ float clampf(float x, float lo, float hi) {
    return fminf(fmaxf(x, lo), hi);
}

__global__ void zero_ints(int* __restrict__ p, int n) {
    int i = blockIdx.x * 256 + threadIdx.x;
    if (i < n) p[i] = 0;
}

// fp16 B repack for CIN=64 layers, frag-major physical k' (= p) layout:
// p < 4096:  tile = p>>8 (mt = tile>>2, ct = tile&3); g = (p>>6)&3;
//            m = (p>>2)&15; i = p&3; bin = mt*16+g*4+i; c = ct*16+m -> cw[bin][c]
// p >= 4096: fw row c = p-4096   (4096..4159; 130 K-steps * 32 = 4160 exactly)
__global__ void repack_wh(const float* __restrict__ cw, const float* __restrict__ fw,
                          _Float16* __restrict__ Wh) {
    int idx = blockIdx.x * 256 + threadIdx.x;
    int total = 4 * 130 * 512;
    if (idx >= total) return;
    int j8 = idx & 7;
    int l = (idx >> 3) & 63;
    int rest = idx >> 9;
    int s = rest % 130;
    int t = rest / 130;
    int p = s * 32 + ((l >> 4) * 8) + j8;
    int co = t * 16 + (l & 15);
    float v = 0.f;
    if (p < 4096) {
        int tile = p >> 8;
        int g = (p >> 6) & 3;
        int m = (p >> 2) & 15;
        int i = p & 3;
        int mt = tile >> 2;
        int ct = tile & 3;
        int bin = mt * 16 + g * 4 + i;
        int c = ct * 16 + m;
        v = cw[(bin * 64 + c) * 64 + co];
    } else if (p < 4160) {
        v = fw[(p - 4096) * 64 + co];
    }
    Wh[idx] = (_Float16)v;
}

// Same p-layout, COUT=2 (layer 3).
__global__ void repack_wh3(const float* __restrict__ cw, const float* __restrict__ fw,
                           _Float16* __restrict__ Wh) {
    int idx = blockIdx.x * 256 + threadIdx.x;
    int total = 130 * 512;
    if (idx >= total) return;
    int j8 = idx & 7;
    int l = (idx >> 3) & 63;
    int s = idx >> 9;
    int p = s * 32 + ((l >> 4) * 8) + j8;
    int co = l & 15;
    float v = 0.f;
    if (co < 2) {
        if (p < 4096) {
            int tile = p >> 8;
            int g = (p >> 6) & 3;
            int m = (p >> 2) & 15;
            int i = p & 3;
            int mt = tile >> 2;
            int ct = tile & 3;
            int bin = mt * 16 + g * 4 + i;
            int c = ct * 16 + m;
            v = cw[(bin * 64 + c) * 2 + co];
        } else if (p < 4160) {
            v = fw[(p - 4096) * 2 + co];
        }
    }
    Wh[idx] = (_Float16)v;
}

// Layer-0 combined weight repack. p<256: bin = p&63, c = p>>6 (Cin=4);
// p in [256,260): dense row c' = p-256; p>=260: pad 0.
// cols co<32 = lin (fw0), co>=32 = conv (cw0).
__global__ void repack_w0h(const float* __restrict__ cw0, const float* __restrict__ fw0,
                           _Float16* __restrict__ Wh) {
    int idx = blockIdx.x * 256 + threadIdx.x;
    int total = 4 * 9 * 512;
    if (idx >= total) return;
    int j8 = idx & 7;
    int l = (idx >> 3) & 63;
    int rest = idx >> 9;
    int s = rest % 9;
    int t = rest / 9;
    int p = s * 32 + ((l >> 4) * 8) + j8;
    int co = t * 16 + (l & 15);
    float v = 0.f;
    if (p < 256) {
        int bin = p & 63;
        int c = p >> 6;
        if (co >= 32) v = cw0[(bin * 4 + c) * 32 + (co - 32)];
    } else if (p < 260) {
        int c = p - 256;
        if (co < 32) v = fw0[c * 32 + co];
    }
    Wh[idx] = (_Float16)v;
}

__global__ void edge_hist(const int* __restrict__ ei, const int* __restrict__ ej,
                          int* __restrict__ counts, int E) {
    int e = blockIdx.x * 256 + threadIdx.x;
    if (e >= E) return;
    int i = ei[e], j = ej[e];
    if (i != j) atomicAdd(&counts[i], 1);
}

__global__ __launch_bounds__(1024) void scan_kernel(const int* __restrict__ counts,
                                                    int* __restrict__ offs,
                                                    int* __restrict__ cursor, int N) {
    __shared__ int sums[1024];
    const int t = threadIdx.x;
    const int per = (N + 1023) / 1024;
    const int lo = t * per;
    const int hi = min(lo + per, N);
    int s = 0;
    for (int i = lo; i < hi; ++i) s += counts[i];
    sums[t] = s;
    __syncthreads();
    for (int d = 1; d < 1024; d <<= 1) {
        int v = (t >= d) ? sums[t - d] : 0;
        __syncthreads();
        sums[t] += v;
        __syncthreads();
    }
    int run = (t > 0) ? sums[t - 1] : 0;
    for (int i = lo; i < hi; ++i) {
        offs[i] = run;
        cursor[i] = run;
        run += counts[i];
    }
    if (t == 1023) offs[N] = sums[1023];
}

// csr_all[e] = uint4:
//   .x = j[0:17) | r0>>1 [17:19) | r1>>1 [19:21) | iv [21:24)
//   .z = fp16x2 {wu0*gv, wu0*fv}   (even u-row r0 taps at iv, iv+1)
//   .w = fp16x2 {wu1*gv, wu1*fv}   (odd  u-row r1 taps at iv, iv+1)
__global__ void edge_scatter(const int* __restrict__ ei, const int* __restrict__ ej,
                             const float* __restrict__ pos, int* __restrict__ cursor,
                             uint4* __restrict__ csr_all, int E) {
    int e = blockIdx.x * 256 + threadIdx.x;
    if (e >= E) return;
    int i = ei[e], j = ej[e];
    if (i == j) return;
    float dx = clampf(pos[i * 2 + 0] - pos[j * 2 + 0], -1.f, 1.f);
    float dy = clampf(pos[i * 2 + 1] - pos[j * 2 + 1], -1.f, 1.f);
    float r = sqrtf(dx * dx + dy * dy + 1e-12f);
    float u = clampf(2.f * r - 1.f, -1.f, 1.f);
    float v = atan2f(dy, dx) * 0.3183098861837907f;  // / pi
    float tu = (u + 1.f) * 3.5f;
    float tv = (v + 1.f) * 3.5f;
    int iu = min(6, max(0, (int)floorf(tu)));
    int iv = min(6, max(0, (int)floorf(tv)));
    float fu = clampf(tu - (float)iu, 0.f, 1.f);
    float fv = clampf(tv - (float)iv, 0.f, 1.f);
    bool even = (iu & 1) == 0;
    int rowi0 = even ? iu : iu + 1;  // even u-row
    int rowi1 = even ? iu + 1 : iu;  // odd u-row
    float wu0 = even ? (1.f - fu) : fu;
    float wu1 = even ? fu : (1.f - fu);
    float gv = 1.f - fv;
    unsigned a0 = (unsigned)__builtin_bit_cast(unsigned short, (_Float16)(wu0 * gv)) |
                  ((unsigned)__builtin_bit_cast(unsigned short, (_Float16)(wu0 * fv)) << 16);
    unsigned a1 = (unsigned)__builtin_bit_cast(unsigned short, (_Float16)(wu1 * gv)) |
                  ((unsigned)__builtin_bit_cast(unsigned short, (_Float16)(wu1 * fv)) << 16);
    int p = atomicAdd(&cursor[i], 1);
    csr_all[p] = make_uint4(
        (unsigned)j | ((unsigned)(rowi0 >> 1) << 17) | ((unsigned)(rowi1 >> 1) << 19) |
            ((unsigned)iv << 21),
        0u, a0, a1);
}

// ---------------------------------------------------------------------------
// Shared phase 1 (verified r4/r7): per-wave 32-edge K-tiles.
//   A = basis [64 bins x 32 e] fp16, zeroed + 4-tap sparse scatter.
//   B = gathered xh rows, subtiled [sub=(e>>2)*4+(c>>4)][e&3][c&15].
//   B-frags via ds_read_b64_tr_b16 chunk-gather (addr = tile_base + m*8).
//   Rule #18: lgkmcnt(0) + sched_barrier(0) between tr reads and MFMAs.
// NO register input pipeline: r13 proved the 128-unified-reg budget is
// exactly full (64 VGPR + 64 AGPR acc) — +40 regs of pipeline state spilled
// (WRITE_SIZE 19->350 MB, dur +43%). This single-buffered form is the
// register-feasible optimum at this block shape.
__device__ __forceinline__ void mom_phase1_64(
    const _Float16* __restrict__ xh, const uint4* __restrict__ csr_all,
    _Float16* Ast, _Float16* Bst, unsigned bst_byte,
    int e0, int e1, int lane, f32x4* acc) {
    const int half = lane >> 5;
    const int el = lane & 31;
    const int q = lane >> 4;
    const int m = lane & 15;
    for (int bs = e0; bs < e1; bs += 32) {
        {  // zero A (4 KB)
            uint4 z4 = make_uint4(0, 0, 0, 0);
#pragma unroll
            for (int zz = 0; zz < 4; ++zz) ((uint4*)Ast)[zz * 64 + lane] = z4;
        }
        int e = bs + el;
        bool ok = e < e1;
        uint4 ca = csr_all[ok ? e : e0];
        int jme = ok ? (int)(ca.x & 0x1FFFF) : -1;
        {
            int iv = (ca.x >> 21) & 7;
            int rowi = half ? (int)((((ca.x >> 19) & 3) << 1) + 1)
                            : (int)(((ca.x >> 17) & 3) << 1);
            h2 wts = __builtin_bit_cast(h2, half ? ca.w : ca.z);
            if (ok) {
                int bin0 = rowi * 8 + iv;
                int bin1 = bin0 + 1;
                int a0 = bin0 * 32 + (((el >> 3) + (bin0 >> 1)) & 3) * 8 + (el & 7);
                int a1 = bin1 * 32 + (((el >> 3) + (bin1 >> 1)) & 3) * 8 + (el & 7);
                Ast[a0] = wts[0];
                Ast[a1] = wts[1];
            }
        }
        // B gather: 4 iters, each stages 8 edges x 64 ch (b128 writes)
#pragma unroll
        for (int it = 0; it < 4; ++it) {
            int ee = it * 8 + (lane >> 3);
            int jj = __shfl(jme, ee);
            int c0 = (lane & 7) * 8;
            uint4 bv = make_uint4(0, 0, 0, 0);
            if (jj >= 0) bv = *(const uint4*)(xh + (size_t)jj * 64 + c0);
            int sub = (ee >> 2) * 4 + (c0 >> 4);
            ((uint4*)Bst)[sub * 8 + (ee & 3) * 2 + ((c0 >> 3) & 1)] = bv;
        }
        // A-frags (b128, compiler-scheduled; stores above alias -> ordered)
        h8 af[4];
#pragma unroll
        for (int mt = 0; mt < 4; ++mt) {
            int binr = mt * 16 + m;
            int aoff = binr * 32 + ((q + (binr >> 1)) & 3) * 8;
            af[mt] = *(const h8*)(Ast + aoff);
        }
        // B-frags via HW transpose read (chunk addr = tile_base + m*8)
        unsigned bb = bst_byte + (unsigned)(q * 1024 + m * 8);
        h8 bf[4];
#pragma unroll
        for (int ct = 0; ct < 4; ++ct) {
            u32x2 lo, hi;
            asm volatile("ds_read_b64_tr_b16 %0, %2 offset:%3\n\t"
                         "ds_read_b64_tr_b16 %1, %2 offset:%4"
                         : "=&v"(lo), "=&v"(hi)
                         : "v"(bb), "i"(ct * 128), "i"(ct * 128 + 512)
                         : "memory");
            u32x4 t;
            t[0] = lo[0]; t[1] = lo[1]; t[2] = hi[0]; t[3] = hi[1];
            bf[ct] = __builtin_bit_cast(h8, t);
        }
        asm volatile("s_waitcnt lgkmcnt(0)" ::: "memory");
        __builtin_amdgcn_sched_barrier(0);
        __builtin_amdgcn_s_setprio(1);
#pragma unroll
        for (int mt = 0; mt < 4; ++mt)
#pragma unroll
            for (int ct = 0; ct < 4; ++ct)
                acc[mt * 4 + ct] = __builtin_amdgcn_mfma_f32_16x16x32_f16(
                    af[mt], bf[ct], acc[mt * 4 + ct], 0, 0, 0);
        __builtin_amdgcn_s_setprio(0);
    }
}

// Writeback acc[16] -> frag-major p-layout (p = t*256 + g*64 + m*4 + i), fp16.
__device__ __forceinline__ void mom_writeback_64(const f32x4* acc, _Float16* momrow,
                                                 int lane) {
#pragma unroll
    for (int t = 0; t < 16; ++t) {
        h2 lo = {(_Float16)acc[t][0], (_Float16)acc[t][1]};
        h2 hi = {(_Float16)acc[t][2], (_Float16)acc[t][3]};
        h2* dst = (h2*)(momrow + t * 256 + (lane >> 4) * 64 + (lane & 15) * 4);
        dst[0] = lo;
        dst[1] = hi;
    }
}

// ---------------------------------------------------------------------------
// Layers 1..2 (CIN=64, COUT=64). Final structure (r7/r12, session best):
// TM=16, 1024 thr, 133.9 KB LDS, 1 block/CU. Alternatives all measured worse:
// r9 TM=8 (+45 us: doubled per-block Wh L2 traffic), r10 dual-node ILP
// (+40 us: VGPR 120 halved occupancy), r11 split-stream+perm (+12 us),
// r13 register pipeline (+73 us: spill). {LDS, regs, waves} all saturated.
// MODE 1: out32 = gemm+cb+fb (residual src), xh_out = fp16(relu(out32))
// MODE 2: res += x32 (residual); only xh_out written.
template <int MODE>
__global__ __launch_bounds__(1024, 4) void conv64_mfma(
    const _Float16* __restrict__ xh, const float* __restrict__ x32,
    const _Float16* __restrict__ Wh,
    const float* __restrict__ cb, const float* __restrict__ fb,
    const int* __restrict__ offs, const uint4* __restrict__ csr_all,
    float* __restrict__ out32, _Float16* __restrict__ xh_out, int nNodes) {
    constexpr int TM = 16;
    constexpr int KSTEPS = 130;
    constexpr int RSH = 4184;            // halfs per node row (8368 B)
    extern __shared__ _Float16 smem[];   // 16 * 4184 * 2 = 133888 B
    const int tid = threadIdx.x;
    const int w = tid >> 6;
    const int lane = tid & 63;
    const int base = blockIdx.x * TM;
    const int n = base + w;

    _Float16* Ast = smem + w * RSH;      // 2048 halfs staging (overlays mom row)
    _Float16* Bst = Ast + 2048;          // 2048 halfs
    const unsigned bst_byte = (unsigned)((w * RSH + 2048) * 2);

    f32x4 acc[16] = {{0, 0, 0, 0}, {0, 0, 0, 0}, {0, 0, 0, 0}, {0, 0, 0, 0},
                     {0, 0, 0, 0}, {0, 0, 0, 0}, {0, 0, 0, 0}, {0, 0, 0, 0},
                     {0, 0, 0, 0}, {0, 0, 0, 0}, {0, 0, 0, 0}, {0, 0, 0, 0},
                     {0, 0, 0, 0}, {0, 0, 0, 0}, {0, 0, 0, 0}, {0, 0, 0, 0}};

    if (n < nNodes) {
        mom_phase1_64(xh, csr_all, Ast, Bst, bst_byte, offs[n], offs[n + 1], lane, acc);
        mom_writeback_64(acc, smem + w * RSH, lane);
        smem[w * RSH + 4096 + lane] = xh[(size_t)n * 64 + lane];  // dense row
    }

    // ---- phase 2: K-chunk for this wave (130 = 2*9 + 14*8)
    const int s0 = w * 8 + min(w, 2);
    const int s_end = s0 + 8 + (w < 2 ? 1 : 0);
    const int quad = lane >> 4;
    const _Float16* arow = smem + (lane & 15) * RSH;

    const uint4* Bp = (const uint4*)Wh;
    uint4 b0[4], b1[4];
#pragma unroll
    for (int t = 0; t < 4; ++t) {  // global prefetch (no LDS dep) before barrier
        b0[t] = Bp[((size_t)t * KSTEPS + s0) * 64 + lane];
        b1[t] = Bp[((size_t)t * KSTEPS + s0 + 1) * 64 + lane];
    }
    __syncthreads();
    f32x4 acc2[4] = {{0, 0, 0, 0}, {0, 0, 0, 0}, {0, 0, 0, 0}, {0, 0, 0, 0}};
    for (int s = s0; s < s_end; ++s) {
        uint4 bq[4];
#pragma unroll
        for (int t = 0; t < 4; ++t) {
            bq[t] = b0[t];
            b0[t] = b1[t];
            if (s + 2 < s_end) b1[t] = Bp[((size_t)t * KSTEPS + s + 2) * 64 + lane];
        }
        h8 a = *(const h8*)(arow + s * 32 + quad * 8);
#pragma unroll
        for (int t = 0; t < 4; ++t)
            acc2[t] = __builtin_amdgcn_mfma_f32_16x16x32_f16(a, __builtin_bit_cast(h8, bq[t]),
                                                             acc2[t], 0, 0, 0);
    }
    __syncthreads();  // moments dead -> reuse as reduce scratch (64 KB)
    f32x4* red = (f32x4*)smem;
#pragma unroll
    for (int t = 0; t < 4; ++t) red[(w * 4 + t) * 64 + lane] = acc2[t];
    __syncthreads();
    if (w < 4) {
        f32x4 s = {0, 0, 0, 0};
#pragma unroll
        for (int g = 0; g < 16; ++g) s += red[(g * 4 + w) * 64 + lane];
        const int co = w * 16 + (lane & 15);
#pragma unroll
        for (int i = 0; i < 4; ++i) {
            int nn = base + quad * 4 + i;
            if (nn < nNodes) {
                float res = s[i] + cb[co] + fb[co];
                if (MODE == 2) res += x32[(size_t)nn * 64 + co];
                if (MODE == 1) out32[(size_t)nn * 64 + co] = res;
                xh_out[(size_t)nn * 64 + co] = (_Float16)fmaxf(res, 0.f);
            }
        }
    }
}

// ---------------------------------------------------------------------------
// Layer 3 (CIN=64, COUT=2): same phase 1 as conv64; phase 2 = 1 MFMA t-tile
// (cols 0..1 real). out = (gemm + cb3 + fb3) / 128.
__global__ __launch_bounds__(1024, 4) void conv_last_mfma(
    const _Float16* __restrict__ xh, const _Float16* __restrict__ Wh3,
    const float* __restrict__ cb3, const float* __restrict__ fb3,
    const int* __restrict__ offs, const uint4* __restrict__ csr_all,
    float* __restrict__ out, int nNodes) {
    constexpr int TM = 16;
    constexpr int RSH = 4184;
    extern __shared__ _Float16 smem[];   // 133888 B
    const int tid = threadIdx.x;
    const int w = tid >> 6;
    const int lane = tid & 63;
    const int base = blockIdx.x * TM;
    const int n = base + w;

    _Float16* Ast = smem + w * RSH;
    _Float16* Bst = Ast + 2048;
    const unsigned bst_byte = (unsigned)((w * RSH + 2048) * 2);

    f32x4 acc[16] = {{0, 0, 0, 0}, {0, 0, 0, 0}, {0, 0, 0, 0}, {0, 0, 0, 0},
                     {0, 0, 0, 0}, {0, 0, 0, 0}, {0, 0, 0, 0}, {0, 0, 0, 0},
                     {0, 0, 0, 0}, {0, 0, 0, 0}, {0, 0, 0, 0}, {0, 0, 0, 0},
                     {0, 0, 0, 0}, {0, 0, 0, 0}, {0, 0, 0, 0}, {0, 0, 0, 0}};

    if (n < nNodes) {
        mom_phase1_64(xh, csr_all, Ast, Bst, bst_byte, offs[n], offs[n + 1], lane, acc);
        mom_writeback_64(acc, smem + w * RSH, lane);
        smem[w * RSH + 4096 + lane] = xh[(size_t)n * 64 + lane];  // dense (relu'd)
    }

    const int s0 = w * 8 + min(w, 2);
    const int s_end = s0 + 8 + (w < 2 ? 1 : 0);
    const int quad = lane >> 4;
    const _Float16* arow = smem + (lane & 15) * RSH;
    const uint4* Bp = (const uint4*)Wh3;

    __syncthreads();
    f32x4 acc2 = {0, 0, 0, 0};
    for (int s = s0; s < s_end; ++s) {
        uint4 bq = Bp[(size_t)s * 64 + lane];
        h8 a = *(const h8*)(arow + s * 32 + quad * 8);
        acc2 = __builtin_amdgcn_mfma_f32_16x16x32_f16(a, __builtin_bit_cast(h8, bq),
                                                      acc2, 0, 0, 0);
    }
    __syncthreads();
    f32x4* red = (f32x4*)smem;
    red[w * 64 + lane] = acc2;
    __syncthreads();
    if (w == 0) {
        f32x4 s = {0, 0, 0, 0};
#pragma unroll
        for (int g = 0; g < 16; ++g) s += red[g * 64 + lane];
        const int co = lane & 15;
        if (co < 2) {
#pragma unroll
            for (int i = 0; i < 4; ++i) {
                int nn = base + quad * 4 + i;
                if (nn < nNodes)
                    out[nn * 2 + co] = (s[i] + cb3[co] + fb3[co]) * (1.f / 128.f);
            }
        }
    }
}

// ---------------------------------------------------------------------------
// Layer 0 (CIN=4, raw f32 x, no relu): shrunk moment-GEMM (r12 version).
__global__ __launch_bounds__(1024, 4) void conv0_mfma(
    const float* __restrict__ xf, const _Float16* __restrict__ W0h,
    const float* __restrict__ cb0, const float* __restrict__ fb0,
    const int* __restrict__ offs, const uint4* __restrict__ csr_all,
    _Float16* __restrict__ xh_out, int nNodes) {
    constexpr int TM = 16;
    constexpr int RSH0 = 296;
    constexpr int MOMSZ = 16 * RSH0;     // 4736 halfs
    extern __shared__ _Float16 smem[];   // (4736 + 16*2560)*2 = 91392 B
    const int tid = threadIdx.x;
    const int w = tid >> 6;
    const int lane = tid & 63;
    const int base = blockIdx.x * TM;
    const int n = base + w;

    _Float16* Ast = smem + MOMSZ + w * 2560;
    _Float16* Bst = Ast + 2048;
    _Float16* momrow = smem + w * RSH0;
    const unsigned bst_byte = (unsigned)((MOMSZ + w * 2560 + 2048) * 2);

    f32x4 acc[4] = {{0, 0, 0, 0}, {0, 0, 0, 0}, {0, 0, 0, 0}, {0, 0, 0, 0}};

    if (n < nNodes) {
        const int e0 = offs[n], e1 = offs[n + 1];
        const int half = lane >> 5;
        const int el = lane & 31;
        const int q = lane >> 4;
        const int m = lane & 15;
        for (int bs = e0; bs < e1; bs += 32) {
            {  // zero A
                uint4 z4 = make_uint4(0, 0, 0, 0);
#pragma unroll
                for (int zz = 0; zz < 4; ++zz) ((uint4*)Ast)[zz * 64 + lane] = z4;
            }
            int e = bs + el;
            bool ok = e < e1;
            uint4 ca = csr_all[ok ? e : e0];
            int jme = ok ? (int)(ca.x & 0x1FFFF) : -1;
            {
                int iv = (ca.x >> 21) & 7;
                int rowi = half ? (int)((((ca.x >> 19) & 3) << 1) + 1)
                                : (int)(((ca.x >> 17) & 3) << 1);
                h2 wts = __builtin_bit_cast(h2, half ? ca.w : ca.z);
                if (ok) {
                    int bin0 = rowi * 8 + iv;
                    int bin1 = bin0 + 1;
                    int a0 = bin0 * 32 + (((el >> 3) + (bin0 >> 1)) & 3) * 8 + (el & 7);
                    int a1 = bin1 * 32 + (((el >> 3) + (bin1 >> 1)) & 3) * 8 + (el & 7);
                    Ast[a0] = wts[0];
                    Ast[a1] = wts[1];
                }
            }
            // B: one edge per half-0 lane; 4 real cols + 12 zeros.
            if (half == 0) {
                float4 xj = make_float4(0.f, 0.f, 0.f, 0.f);
                if (jme >= 0) xj = *(const float4*)(xf + (size_t)jme * 4);
                h2 d0 = {(_Float16)xj.x, (_Float16)xj.y};
                h2 d1 = {(_Float16)xj.z, (_Float16)xj.w};
                uint4 bv = make_uint4(__builtin_bit_cast(unsigned, d0),
                                      __builtin_bit_cast(unsigned, d1), 0u, 0u);
                uint4* dst = (uint4*)Bst + (el >> 2) * 8 + (el & 3) * 2;
                dst[0] = bv;
                dst[1] = make_uint4(0, 0, 0, 0);
            }
            // A-frags
            h8 af[4];
#pragma unroll
            for (int mt = 0; mt < 4; ++mt) {
                int binr = mt * 16 + m;
                int aoff = binr * 32 + ((q + (binr >> 1)) & 3) * 8;
                af[mt] = *(const h8*)(Ast + aoff);
            }
            // B-frag via tr-read: chunk addr q*256 + m*8; subs 2q / 2q+1
            unsigned bb = bst_byte + (unsigned)(q * 256 + m * 8);
            u32x2 lo, hi;
            asm volatile("ds_read_b64_tr_b16 %0, %2 offset:0\n\t"
                         "ds_read_b64_tr_b16 %1, %2 offset:128"
                         : "=&v"(lo), "=&v"(hi)
                         : "v"(bb)
                         : "memory");
            u32x4 tt;
            tt[0] = lo[0]; tt[1] = lo[1]; tt[2] = hi[0]; tt[3] = hi[1];
            h8 b = __builtin_bit_cast(h8, tt);
            asm volatile("s_waitcnt lgkmcnt(0)" ::: "memory");
            __builtin_amdgcn_sched_barrier(0);
            __builtin_amdgcn_s_setprio(1);
#pragma unroll
            for (int mt = 0; mt < 4; ++mt)
                acc[mt] = __builtin_amdgcn_mfma_f32_16x16x32_f16(af[mt], b, acc[mt], 0, 0, 0);
            __builtin_amdgcn_s_setprio(0);
        }
        // writeback: p = bin + 64*c, only c = lane&15 < 4 valid
        if ((lane & 15) < 4) {
#pragma unroll
            for (int mt = 0; mt < 4; ++mt) {
                _Float16* dst = momrow + mt * 16 + (lane >> 4) * 4 + 64 * (lane & 15);
                ((h2*)dst)[0] = h2{(_Float16)acc[mt][0], (_Float16)acc[mt][1]};
                ((h2*)dst)[1] = h2{(_Float16)acc[mt][2], (_Float16)acc[mt][3]};
            }
        }
        if (lane < 7) {  // zero pad p in [260, 288)
            h2 z = {(_Float16)0.f, (_Float16)0.f};
            h2* zp = (h2*)(momrow + 260 + lane * 4);
            zp[0] = z;
            zp[1] = z;
        }
        if (lane < 4) momrow[256 + lane] = (_Float16)xf[(size_t)n * 4 + lane];  // dense raw
    }

    // phase 2: 9 K-steps over 16 waves (waves 9..15 idle)
    const int quad = lane >> 4;
    const _Float16* arow = smem + (lane & 15) * RSH0;
    const uint4* Bp = (const uint4*)W0h;
    __syncthreads();
    f32x4 acc2[4] = {{0, 0, 0, 0}, {0, 0, 0, 0}, {0, 0, 0, 0}, {0, 0, 0, 0}};
    const int s0 = min(w, 9), s_end = min(w + 1, 9);
    for (int s = s0; s < s_end; ++s) {
        uint4 bq[4];
#pragma unroll
        for (int t = 0; t < 4; ++t) bq[t] = Bp[((size_t)t * 9 + s) * 64 + lane];
        h8 a = *(const h8*)(arow + s * 32 + quad * 8);
#pragma unroll
        for (int t = 0; t < 4; ++t)
            acc2[t] = __builtin_amdgcn_mfma_f32_16x16x32_f16(a, __builtin_bit_cast(h8, bq[t]),
                                                             acc2[t], 0, 0, 0);
    }
    __syncthreads();
    f32x4* red = (f32x4*)(smem + MOMSZ);  // overlays dead staging
#pragma unroll
    for (int t = 0; t < 4; ++t) red[(w * 4 + t) * 64 + lane] = acc2[t];
    __syncthreads();
    if (w < 4) {
        f32x4 s = {0, 0, 0, 0};
#pragma unroll
        for (int g = 0; g < 16; ++g) s += red[(g * 4 + w) * 64 + lane];
        const int co = w * 16 + (lane & 15);
        const float bias = (co < 32) ? fb0[co] : cb0[co - 32];
#pragma unroll
        for (int i = 0; i < 4; ++i) {
            int nn = base + quad * 4 + i;
            if (nn < nNodes)
                xh_out[(size_t)nn * 64 + co] = (_Float16)fmaxf(s[i] + bias, 0.f);
        }
    }
}

extern "C" void kernel_launch(void* const* d_in, const int* in_sizes, int n_in,
                              void* d_out, int out_size, void* d_ws, size_t ws_size,
                              hipStream_t stream) {
    const float* pos = (const float*)d_in[0];
    const float* feat = (const float*)d_in[1];
    const int* ei = (const int*)d_in[2];
    const int* ej = (const int*)d_in[3];
    const float* cw0 = (const float*)d_in[4];
    const float* cb0 = (const float*)d_in[5];
    const float* fw0 = (const float*)d_in[6];
    const float* fb0 = (const float*)d_in[7];
    const float* cw1 = (const float*)d_in[8];
    const float* cb1 = (const float*)d_in[9];
    const float* fw1 = (const float*)d_in[10];
    const float* fb1 = (const float*)d_in[11];
    const float* cw2 = (const float*)d_in[12];
    const float* cb2 = (const float*)d_in[13];
    const float* fw2 = (const float*)d_in[14];
    const float* fb2 = (const float*)d_in[15];
    const float* cw3 = (const float*)d_in[16];
    const float* cb3 = (const float*)d_in[17];
    const float* fw3 = (const float*)d_in[18];
    const float* fb3 = (const float*)d_in[19];
    float* outp = (float*)d_out;

    const int N = in_sizes[0] / 2;
    const int E = in_sizes[2];

    char* wsp = (char*)d_ws;
    size_t off = 0;
    auto alloc = [&](size_t bytes) -> void* {
        void* p = wsp + off;
        off = (off + bytes + 255) & ~(size_t)255;
        return p;
    };
    int* counts = (int*)alloc((size_t)N * 4);
    int* offs = (int*)alloc((size_t)(N + 1) * 4);
    int* cursor = (int*)alloc((size_t)N * 4);
    uint4* csr_all = (uint4*)alloc((size_t)E * 16);
    float* ansB = (float*)alloc((size_t)N * 64 * 4);       // layer-1 f32 (residual)
    _Float16* xh0 = (_Float16*)alloc((size_t)N * 64 * 2);  // conv0 out (relu fp16)
    _Float16* xhB = (_Float16*)alloc((size_t)N * 64 * 2);  // layer-1 relu fp16
    _Float16* xhC = (_Float16*)alloc((size_t)N * 64 * 2);  // layer-2 relu fp16
    _Float16* Wh1 = (_Float16*)alloc((size_t)4 * 130 * 512 * 2);
    _Float16* Wh2 = (_Float16*)alloc((size_t)4 * 130 * 512 * 2);
    _Float16* Wh3 = (_Float16*)alloc((size_t)130 * 512 * 2);
    _Float16* W0h = (_Float16*)alloc((size_t)4 * 9 * 512 * 2);
    (void)ws_size;
    (void)n_in;
    (void)out_size;

    const int BIG_LDS = 16 * 4184 * 2;             // 133888 B, 1 block/CU
    const int LDS0 = (16 * 296 + 16 * 2560) * 2;   // 91392 B
    hipFuncSetAttribute((const void*)&conv64_mfma<1>,
                        hipFuncAttributeMaxDynamicSharedMemorySize, BIG_LDS);
    hipFuncSetAttribute((const void*)&conv64_mfma<2>,
                        hipFuncAttributeMaxDynamicSharedMemorySize, BIG_LDS);
    hipFuncSetAttribute((const void*)&conv_last_mfma,
                        hipFuncAttributeMaxDynamicSharedMemorySize, BIG_LDS);
    hipFuncSetAttribute((const void*)&conv0_mfma,
                        hipFuncAttributeMaxDynamicSharedMemorySize, LDS0);

    zero_ints<<<dim3((N + 255) / 256), dim3(256), 0, stream>>>(counts, N);
    const int RT = 4 * 130 * 512;
    repack_wh<<<dim3((RT + 255) / 256), dim3(256), 0, stream>>>(cw1, fw1, Wh1);
    repack_wh<<<dim3((RT + 255) / 256), dim3(256), 0, stream>>>(cw2, fw2, Wh2);
    repack_wh3<<<dim3((130 * 512 + 255) / 256), dim3(256), 0, stream>>>(cw3, fw3, Wh3);
    repack_w0h<<<dim3((4 * 9 * 512 + 255) / 256), dim3(256), 0, stream>>>(cw0, fw0, W0h);
    edge_hist<<<dim3((E + 255) / 256), dim3(256), 0, stream>>>(ei, ej, counts, E);
    scan_kernel<<<dim3(1), dim3(1024), 0, stream>>>(counts, offs, cursor, N);
    edge_scatter<<<dim3((E + 255) / 256), dim3(256), 0, stream>>>(ei, ej, pos, cursor, csr_all, E);

    const int nb = (N + 15) / 16;
    conv0_mfma<<<dim3(nb), dim3(1024), LDS0, stream>>>(
        feat, W0h, cb0, fb0, offs, csr_all, xh0, N);
    conv64_mfma<1><<<dim3(nb), dim3(1024), BIG_LDS, stream>>>(
        xh0, (const float*)nullptr, Wh1, cb1, fb1, offs, csr_all, ansB, xhB, N);
    conv64_mfma<2><<<dim3(nb), dim3(1024), BIG_LDS, stream>>>(
        xhB, ansB, Wh2, cb2, fb2, offs, csr_all, (float*)nullptr, xhC, N);
    conv_last_mfma<<<dim3(nb), dim3(1024), BIG_LDS, stream>>>(
        xhC, Wh3, cb3, fb3, offs, csr_all, outp, N);
}